// Round 4
// baseline (168.695 us; speedup 1.0000x reference)
//
#include <hip/hip_runtime.h>
#include <stdint.h>

// Problem constants (B=16, A=3, H=W=76, ATTR=5+80=85)
// Input:  fp32, shape (16, 255, 76, 76)   = 23,566,080 floats (94.3 MB)
// Output: fp32, shape (16, 3, 76, 76, 85) = 23,566,080 floats (94.3 MB)
#define NB       16
#define NA       3
#define HH_      76
#define WW_      76
#define S_TOT    (HH_ * WW_)          // 5776 spatial positions
#define ATTR     85
#define TILE_S   76                   // spatial positions per block (1 image row)
#define TILES    (S_TOT / TILE_S)     // 76
#define NTHREADS 512
#define QUADS    22                   // ceil(85/4) attrib quads per spatial pos
#define UNITS1   (QUADS * TILE_S)     // 1672 phase-1 units (one s x 4 attribs)
#define UNITS2   (TILE_S * ATTR / 4)  // 1615 phase-2 float4 granules
#define NB1      4                    // ceil(UNITS1 / NTHREADS)
#define NB2      4                    // ceil(UNITS2 / NTHREADS)
#define LOG2E    1.44269504088896340f

typedef __attribute__((ext_vector_type(4))) float float4v;

__device__ __forceinline__ float fast_sigmoid(float x) {
    // 1 / (1 + e^-x) = rcp(1 + exp2(-x*log2e)); x ~ N(0,1), |x| <= ~6, finite
    float e = __builtin_amdgcn_exp2f(x * (-LOG2E));
    return __builtin_amdgcn_rcpf(1.0f + e);
}

// R4 theory: R0/R2/R3 all pinned at ~59 us across wildly different occupancy /
// conflict / tile configs -> the invariant was the NONTEMPORAL store path.
// Writes ran at only 1.6 TB/s (2.6 B/cyc/CU) while the harness memset writes at
// 6.5 TB/s through the cache path: NT bypasses L2, so each CU is limited by its
// small uncached-write queue (N_outstanding x 64 B per ~400 ns RTT ~ 5-6 GB/s/CU,
// exactly what we measure) -- a per-CU LATENCY limit, which is why nothing else
// moved the needle. This round: single change, store through L2 (no NT hint).
__global__ __launch_bounds__(NTHREADS, 8)
void yolo_layer_kernel(const float* __restrict__ in,
                       float* __restrict__ out) {
    // LDS holds the fp32 output tile verbatim: [TILE_S][ATTR], unpadded.
    __shared__ __attribute__((aligned(16))) float lds[TILE_S * ATTR]; // 25,840 B

    const int tid  = threadIdx.x;
    const int tile = blockIdx.x;          // 0..75  (spatial tile = one image row)
    const int BA   = blockIdx.y;          // 0..47  (b*3 + a)
    const int a    = BA % NA;
    const int s0   = tile * TILE_S;

    // anchor constants (faithful to reference's off-by-one anchor_h indexing:
    // ANCHOR_W = [10,13,16], ANCHOR_H = [13,16,30])
    const float aw = (a == 0) ? 10.0f : (a == 1) ? 13.0f : 16.0f;
    const float ah = (a == 0) ? 13.0f : (a == 1) ? 16.0f : 30.0f;
    const float cw = aw * (1.0f / 608.0f);
    const float ch = ah * (1.0f / 608.0f);

    const float* inb = in + (size_t)BA * (ATTR * S_TOT) + s0;

    // ---------- Phase 1a: issue ALL loads back-to-back (16 b32 loads/thread) ----
    // Unit u = g*TILE_S + s : one spatial position s, attribs 4g..4g+3.
    // Lanes are consecutive in s -> each load instr covers 256 contiguous bytes.
    float v[NB1][4];
    #pragma unroll
    for (int i = 0; i < NB1; ++i) {
        int u  = tid + i * NTHREADS;
        int uc = (u < UNITS1) ? u : 0;       // clamp tail to safe in-bounds unit
        int g  = uc / TILE_S;
        int s  = uc - g * TILE_S;
        const float* p = inb + s;
        #pragma unroll
        for (int q = 0; q < 4; ++q) {
            int k = 4 * g + q;
            if (k > ATTR - 1) k = ATTR - 1;  // g==21 quad clamps to attrib 84 (same line, L1 hit)
            v[i][q] = p[(size_t)k * S_TOT];
        }
    }

    // ---------- Phase 1b: math + LDS scatter (conflict-free) ----------
    // Write 4 consecutive words at lds[s*85 + 4g + q]: lane stride = 85 words
    // (odd) -> all 32 banks covered, 2 lanes/bank = free aliasing.
    #pragma unroll
    for (int i = 0; i < NB1; ++i) {
        int u = tid + i * NTHREADS;
        if (u >= UNITS1) break;              // only trims the last batch slice
        int g = u / TILE_S;
        int s = u - g * TILE_S;

        float r[4];
        if (g != 0) {
            // conf + class scores: plain sigmoid (21/22 of units, convergent)
            #pragma unroll
            for (int q = 0; q < 4; ++q) r[q] = fast_sigmoid(v[i][q]);
        } else {
            // attribs 0..3 = tx,ty,tw,th for spatial position sp
            int sp = s0 + s;                 // global spatial index = h*76 + w
            int hy = sp / WW_;
            int wx = sp - hy * WW_;
            r[0] = ((float)wx + fast_sigmoid(v[i][0])) * (1.0f / 76.0f);
            r[1] = ((float)hy + fast_sigmoid(v[i][1])) * (1.0f / 76.0f);
            r[2] = __builtin_amdgcn_exp2f(v[i][2] * LOG2E) * cw;
            r[3] = __builtin_amdgcn_exp2f(v[i][3] * LOG2E) * ch;
        }

        float* lp = &lds[s * ATTR + 4 * g];
        #pragma unroll
        for (int q = 0; q < 4; ++q) {
            if (4 * g + q < ATTR) lp[q] = r[q];   // drops the 3 pad lanes of g==21
        }
    }

    __syncthreads();

    // ---------- Phase 2: contiguous LDS -> global, batched b128 reads,
    // stores through L2 (NT hint removed -- the single change this round).
    // out tile base elem = (BA*5776 + s0)*85 ; divisible by 4 -> 16B aligned
    float4v* outv = (float4v*)(out + ((size_t)BA * S_TOT + s0) * ATTR);
    const float4v* ldsv = (const float4v*)lds;

    float4v w[NB2];
    #pragma unroll
    for (int i = 0; i < NB2; ++i) {
        int u  = tid + i * NTHREADS;
        int uc = (u < UNITS2) ? u : 0;
        w[i] = ldsv[uc];
    }
    #pragma unroll
    for (int i = 0; i < NB2; ++i) {
        int u = tid + i * NTHREADS;
        if (u >= UNITS2) break;
        outv[u] = w[i];                      // plain b128 store via L2
    }
}

extern "C" void kernel_launch(void* const* d_in, const int* in_sizes, int n_in,
                              void* d_out, int out_size, void* d_ws, size_t ws_size,
                              hipStream_t stream) {
    const float* in = (const float*)d_in[0];   // fp32 input
    float* out = (float*)d_out;                // fp32 output

    dim3 grid(TILES, NB * NA);   // (76, 48) = 3648 blocks
    dim3 block(NTHREADS);
    yolo_layer_kernel<<<grid, block, 0, stream>>>(in, out);
}

// Round 5
// 167.036 us; speedup vs baseline: 1.0099x; 1.0099x over previous
//
#include <hip/hip_runtime.h>
#include <stdint.h>

// Problem constants (B=16, A=3, H=W=76, ATTR=5+80=85)
// Input:  fp32, shape (16, 255, 76, 76)   = 23,566,080 floats (94.3 MB)
// Output: fp32, shape (16, 3, 76, 76, 85) = 23,566,080 floats (94.3 MB)
#define NB       16
#define NA       3
#define HH_      76
#define WW_      76
#define S_TOT    (HH_ * WW_)          // 5776 spatial positions
#define ATTR     85
#define TILE_S   76                   // spatial positions per block (1 image row)
#define TILES    (S_TOT / TILE_S)     // 76
#define NTHREADS 512
#define NWAVES   (NTHREADS / 64)      // 8
#define TW       (ATTR * TILE_S)      // 6460 words per raw input tile
#define NSTG     ((TW + 63) / 64)     // 102 global_load_lds instructions per block
#define NSTGW    ((NSTG + NWAVES - 1) / NWAVES)  // 13 per wave
#define LDSW     (NSTG * 64)          // 6528 words = 26,112 B (pad tail never read)
#define UNITS2   (TW / 4)             // 1615 output float4 granules
#define NB2      4                    // ceil(UNITS2 / NTHREADS)
#define LOG2E    1.44269504088896340f

typedef __attribute__((ext_vector_type(4))) float float4v;

__device__ __forceinline__ float fast_sigmoid(float x) {
    // 1 / (1 + e^-x) = rcp(1 + exp2(-x*log2e)); x ~ N(0,1), |x| <= ~6, finite
    float e = __builtin_amdgcn_exp2f(x * (-LOG2E));
    return __builtin_amdgcn_rcpf(1.0f + e);
}

// R5 theory: all prior rounds (59 us invariant) had ~1 outstanding load/wave --
// the compiler sank the "batched" loads to their uses (VGPR=20 proves it), so
// both HBM streams ran latency-bound at ~2.6 TB/s and the two phases were
// serial: 63/2.66 + 94/2.66 = 59 us. Fix: async global_load_lds staging (zero
// VGPR, un-sinkable, all 102 load instrs in flight per block) + math on the
// phase-2 LDS->reg path + direct coalesced stores. LDS layout is swizzled via
// the per-lane GLOBAL source address (rule 21): physical word
// A(k,s) = k*76 + (s + (k>>2)) % 76, so the phase-2 transposed read has lane
// stride 305 words = 17 mod 32 -> all 32 banks, ~2/bank = free (the naive
// layout would be 2 banks -> ~32-way conflict).
__global__ __launch_bounds__(NTHREADS, 8)
void yolo_layer_kernel(const float* __restrict__ in,
                       float* __restrict__ out) {
    __shared__ __attribute__((aligned(16))) float lds[LDSW];  // raw swizzled tile

    const int tid  = threadIdx.x;
    const int lane = tid & 63;
    const int wv   = tid >> 6;
    const int tile = blockIdx.x;          // 0..75 = image row j (hy == tile!)
    const int BA   = blockIdx.y;          // 0..47  (b*3 + a)
    const int a    = BA % NA;
    const int s0   = tile * TILE_S;

    // anchor constants (faithful to reference's off-by-one anchor_h indexing:
    // ANCHOR_W = [10,13,16], ANCHOR_H = [13,16,30])
    const float aw = (a == 0) ? 10.0f : (a == 1) ? 13.0f : 16.0f;
    const float ah = (a == 0) ? 13.0f : (a == 1) ? 16.0f : 30.0f;
    const float cw = aw * (1.0f / 608.0f);
    const float ch = ah * (1.0f / 608.0f);

    const float* inb = in + (size_t)BA * (ATTR * S_TOT) + s0;

    // ---------- Phase 1: async raw staging, 102 global_load_lds, no VGPR dest.
    // Instr j writes LDS words [64j, 64j+64); lane l supplies the global source
    // for physical word p = 64j + l:  k = p/76, t = p%76, s = (t - (k>>2)) mod 76.
    // All instructions issue back-to-back; the only drain is __syncthreads().
    #pragma unroll
    for (int i = 0; i < NSTGW; ++i) {
        int j = wv + i * NWAVES;          // wave-uniform
        if (j < NSTG) {
            int p  = j * 64 + lane;
            int pc = (p < TW) ? p : (TW - 1);   // 4 tail lanes of j=101: dup-safe
            int k  = pc / 76;                   // magic-mul div
            int t  = pc - k * 76;
            int s  = t - (k >> 2);
            if (s < 0) s += 76;
            const float* g = inb + (size_t)k * S_TOT + s;
            __builtin_amdgcn_global_load_lds(
                (const __attribute__((address_space(1))) void*)g,
                (__attribute__((address_space(3))) void*)&lds[j * 64],
                4, 0, 0);
        }
    }
    __syncthreads();   // per-wave vmcnt(0) + barrier: tile resident in LDS

    // ---------- Phase 2: swizzled LDS read -> math -> direct coalesced store.
    // Output granule u covers elems 4u..4u+3 of the tile's [s][k] plane
    // (elem = s*85 + k). Each elem independently: s = idx/85, k = idx%85,
    // read lds[k*76 + (s + (k>>2)) % 76].
    float4v* outv = (float4v*)(out + ((size_t)BA * S_TOT + s0) * ATTR);

    #pragma unroll
    for (int i = 0; i < NB2; ++i) {
        int u = tid + i * NTHREADS;
        if (u >= UNITS2) break;           // only trims the last slice

        float r[4];
        #pragma unroll
        for (int e = 0; e < 4; ++e) {
            int idx = 4 * u + e;          // tile elem = s*85 + k
            int s   = idx / 85;           // magic-mul div
            int k   = idx - s * 85;
            int t   = s + (k >> 2);
            if (t >= 76) t -= 76;
            float x = lds[k * 76 + t];

            if (k >= 4) {
                r[e] = fast_sigmoid(x);           // conf + classes (95% of elems)
            } else if (k == 0) {
                r[e] = ((float)s + fast_sigmoid(x)) * (1.0f / 76.0f);   // bx (wx = s)
            } else if (k == 1) {
                r[e] = ((float)tile + fast_sigmoid(x)) * (1.0f / 76.0f); // by (hy = tile)
            } else {
                float ex = __builtin_amdgcn_exp2f(x * LOG2E);
                r[e] = ex * ((k == 2) ? cw : ch);  // bw / bh
            }
        }

        float4v w = { r[0], r[1], r[2], r[3] };
        outv[u] = w;                      // consecutive lanes -> consecutive 16 B
    }
}

extern "C" void kernel_launch(void* const* d_in, const int* in_sizes, int n_in,
                              void* d_out, int out_size, void* d_ws, size_t ws_size,
                              hipStream_t stream) {
    const float* in = (const float*)d_in[0];   // fp32 input
    float* out = (float*)d_out;                // fp32 output

    dim3 grid(TILES, NB * NA);   // (76, 48) = 3648 blocks
    dim3 block(NTHREADS);
    yolo_layer_kernel<<<grid, block, 0, stream>>>(in, out);
}